// Round 6
// baseline (183.987 us; speedup 1.0000x reference)
//
#include <hip/hip_runtime.h>

// Shapes: N=8, M=2048 -> 16384 rows; D=128, L=128.
// out0 h: (16384,128) fp32; out1 edge: (8,2048,2048) = e[row] broadcast.
//
// R5 post-mortem: two occupancy doublings both neutral -> compute phase not
// occupancy-bound. Grid==residency meant zero compute/write-drain overlap:
// total = compute + 134MB drain. R6 splits into:
//   A: compute h + e scalars (to d_ws), ~10us
//   B: edge broadcast write shaped like the harness fill kernel (proven
//      6.4 TB/s: plain float4 stores, 1 wave/row, deep oversubscription)

typedef short short8 __attribute__((ext_vector_type(8)));
typedef float floatx4 __attribute__((ext_vector_type(4)));

__device__ __forceinline__ short f2bf(float f) {
    union { float f; unsigned u; } v; v.f = f;
    unsigned r = v.u + 0x7fffu + ((v.u >> 16) & 1u);   // RNE
    return (short)(r >> 16);
}

// d_ws layout: shorts W1T[256][128] at 0      (w1n^T,  64KB)
//                     W2T[128][256] at 32768  (w2n^T,  64KB)
//                     WET[128][128] at 65536  ((w1e_top+w1e_bot)^T, 32KB)
//              float  es[16384]     at byte 163840 (64KB)
// Requires ws_size >= 229376 bytes.
__global__ __launch_bounds__(256)
void prep_weights(const float* __restrict__ w1n, const float* __restrict__ w2n,
                  const float* __restrict__ w1e, short* __restrict__ ws)
{
    const int id = blockIdx.x * 256 + threadIdx.x;   // 0..81919
    if (id < 32768) {                                // W1T[n][k] = w1n[k][n]
        const int n = id >> 7, k = id & 127;
        ws[id] = f2bf(w1n[k * 256 + n]);
    } else if (id < 65536) {                         // W2T[n][k] = w2n[k][n]
        const int j = id - 32768;
        const int n = j >> 8, k = j & 255;
        ws[id] = f2bf(w2n[k * 128 + n]);
    } else {                                         // WET[n][k] = sum of halves
        const int j = id - 65536;
        const int n = j >> 7, k = j & 127;
        ws[id] = f2bf(w1e[k * 128 + n] + w1e[(k + 128) * 128 + n]);
    }
}

#define TPB 256
#define ROWS 16
#define XS_STRIDE 136   // 128 + 8 pad (bf16)
#define H1_STRIDE 264   // 256 + 8 pad

// MFMA 16x16x32 bf16 lane mapping:
//   A: lane holds A[m = lane&15][k = (lane>>4)*8 + j], j=0..7
//   B: lane holds B[k = (lane>>4)*8 + j][n = lane&15]
//   C/D: reg r holds D[row = (lane>>4)*4 + r][col = lane&15]
__global__ __launch_bounds__(TPB, 4)
void node_edge_compute(const float* __restrict__ x,
                       const float* __restrict__ b1n, const float* __restrict__ b2n,
                       const float* __restrict__ b1e,
                       const float* __restrict__ w2e, const float* __restrict__ b2e,
                       const short* __restrict__ wt,
                       float* __restrict__ h_out, float* __restrict__ e_ws)
{
    __shared__ short xs[ROWS * XS_STRIDE];
    __shared__ short h1s[ROWS * H1_STRIDE];
    __shared__ short hbs[ROWS * XS_STRIDE];
    __shared__ float partial[4][ROWS];

    const int t = threadIdx.x;
    const int w = t >> 6;          // wave 0..3
    const int l = t & 63;
    const int l15 = l & 15;
    const int quad = l >> 4;
    const int row0 = blockIdx.x * ROWS;

    // ---- load 16x128 fp32 tile, convert to bf16 in LDS ----
    {
        const float4* __restrict__ x4 = (const float4*)(x + (size_t)row0 * 128);
#pragma unroll
        for (int i = 0; i < 2; ++i) {
            const int fi = t + i * TPB;            // 512 float4 total
            const float4 v = x4[fi];
            const int row = fi >> 5, col = (fi & 31) * 4;
            short4 s;
            s.x = f2bf(v.x); s.y = f2bf(v.y); s.z = f2bf(v.z); s.w = f2bf(v.w);
            *(short4*)&xs[row * XS_STRIDE + col] = s;
        }
    }
    __syncthreads();

    // ---- stage 1: h1 = relu(X @ W1n + b1n)   (16x128)@(128x256) ----
    {
        short8 a1[4];
#pragma unroll
        for (int k = 0; k < 4; ++k)
            a1[k] = *(const short8*)&xs[l15 * XS_STRIDE + k * 32 + quad * 8];

        floatx4 acc1[4];
#pragma unroll
        for (int ci = 0; ci < 4; ++ci) {
            const int ct = 4 * w + ci;
            const float b = b1n[ct * 16 + l15];
            acc1[ci] = (floatx4){b, b, b, b};
#pragma unroll
            for (int k = 0; k < 4; ++k) {
                const short8 bf = *(const short8*)(wt + (ct * 16 + l15) * 128 + k * 32 + quad * 8);
                acc1[ci] = __builtin_amdgcn_mfma_f32_16x16x32_bf16(a1[k], bf, acc1[ci], 0, 0, 0);
            }
        }
#pragma unroll
        for (int ci = 0; ci < 4; ++ci) {
            const int ct = 4 * w + ci;
#pragma unroll
            for (int r = 0; r < 4; ++r)
                h1s[(quad * 4 + r) * H1_STRIDE + ct * 16 + l15] = f2bf(fmaxf(acc1[ci][r], 0.f));
        }
    }
    __syncthreads();

    // ---- stage 2: h = h1 @ W2n + b2n   (16x256)@(256x128) ----
    {
        short8 a2[8];
#pragma unroll
        for (int k = 0; k < 8; ++k)
            a2[k] = *(const short8*)&h1s[l15 * H1_STRIDE + k * 32 + quad * 8];

        const short* __restrict__ W2T = wt + 32768;
#pragma unroll
        for (int ci = 0; ci < 2; ++ci) {
            const int ct = 2 * w + ci;
            const float b = b2n[ct * 16 + l15];
            floatx4 acc2 = (floatx4){b, b, b, b};
#pragma unroll
            for (int k = 0; k < 8; ++k) {
                const short8 bf = *(const short8*)(W2T + (ct * 16 + l15) * 256 + k * 32 + quad * 8);
                acc2 = __builtin_amdgcn_mfma_f32_16x16x32_bf16(a2[k], bf, acc2, 0, 0, 0);
            }
#pragma unroll
            for (int r = 0; r < 4; ++r) {
                const int row = quad * 4 + r;
                const float v = acc2[r];
                h_out[(size_t)(row0 + row) * 128 + ct * 16 + l15] = v;
                hbs[row * XS_STRIDE + ct * 16 + l15] = f2bf(v);
            }
        }
    }
    __syncthreads();

    // ---- stage 3+4: t1 = relu(h @ WE + b1e); e = (t1 . w2e + b2e)/2048 ----
    {
        short8 a3[4];
#pragma unroll
        for (int k = 0; k < 4; ++k)
            a3[k] = *(const short8*)&hbs[l15 * XS_STRIDE + k * 32 + quad * 8];

        const short* __restrict__ WET = wt + 65536;
        float p[4] = {0.f, 0.f, 0.f, 0.f};
#pragma unroll
        for (int ci = 0; ci < 2; ++ci) {
            const int ct = 2 * w + ci;
            const float b = b1e[ct * 16 + l15];
            floatx4 acc3 = (floatx4){b, b, b, b};
#pragma unroll
            for (int k = 0; k < 4; ++k) {
                const short8 bf = *(const short8*)(WET + (ct * 16 + l15) * 128 + k * 32 + quad * 8);
                acc3 = __builtin_amdgcn_mfma_f32_16x16x32_bf16(a3[k], bf, acc3, 0, 0, 0);
            }
            const float wv = w2e[ct * 16 + l15];
#pragma unroll
            for (int r = 0; r < 4; ++r)
                p[r] += fmaxf(acc3[r], 0.f) * wv;
        }
#pragma unroll
        for (int off = 8; off >= 1; off >>= 1)
#pragma unroll
            for (int r = 0; r < 4; ++r)
                p[r] += __shfl_xor(p[r], off, 64);
        if (l15 == 0) {
#pragma unroll
            for (int r = 0; r < 4; ++r)
                partial[w][quad * 4 + r] = p[r];
        }
    }
    __syncthreads();
    if (t < ROWS) {
        e_ws[row0 + t] = (partial[0][t] + partial[1][t] + partial[2][t]
                          + partial[3][t] + b2e[0]) * (1.0f / 2048.0f);
    }
}

// ---- kernel B: edge[row, :] = e[row]. One wave per 8KB row, 8 x 1KB plain
// float4 stores (the proven-6.4TB/s fill shape). 4096 blocks x 256 thr. ----
__global__ __launch_bounds__(256)
void edge_broadcast(const float* __restrict__ es, float* __restrict__ edge_out)
{
    const int t = threadIdx.x;
    const int row = blockIdx.x * 4 + (t >> 6);   // 4 rows/block, 1 wave/row
    const int l = t & 63;
    const float ev = es[row];                    // wave-uniform broadcast read
    floatx4* __restrict__ e4 = (floatx4*)(edge_out + (size_t)row * 2048);
    const floatx4 vv = (floatx4){ev, ev, ev, ev};
#pragma unroll
    for (int i = 0; i < 8; ++i)
        e4[i * 64 + l] = vv;
}

extern "C" void kernel_launch(void* const* d_in, const int* in_sizes, int n_in,
                              void* d_out, int out_size, void* d_ws, size_t ws_size,
                              hipStream_t stream) {
    const float* x   = (const float*)d_in[0];
    const float* w1n = (const float*)d_in[1];
    const float* b1n = (const float*)d_in[2];
    const float* w2n = (const float*)d_in[3];
    const float* b2n = (const float*)d_in[4];
    const float* w1e = (const float*)d_in[5];
    const float* b1e = (const float*)d_in[6];
    const float* w2e = (const float*)d_in[7];
    const float* b2e = (const float*)d_in[8];

    float* h_out    = (float*)d_out;                              // (8,2048,128)
    float* edge_out = (float*)d_out + (size_t)8 * 2048 * 128;     // (8,2048,2048)
    short* wt       = (short*)d_ws;                               // 160 KB bf16 weights
    float* e_ws     = (float*)((char*)d_ws + 163840);             // 64 KB e scalars

    prep_weights<<<dim3(320), dim3(256), 0, stream>>>(w1n, w2n, w1e, wt);
    node_edge_compute<<<dim3(1024), dim3(TPB), 0, stream>>>(
        x, b1n, b2n, b1e, w2e, b2e, wt, h_out, e_ws);
    edge_broadcast<<<dim3(4096), dim3(256), 0, stream>>>(e_ws, edge_out);
}

// Round 7
// 173.826 us; speedup vs baseline: 1.0585x; 1.0585x over previous
//
#include <hip/hip_runtime.h>

// Shapes: N=8, M=2048 -> 16384 rows; D=128, L=128.
// out0 h: (16384,128) fp32; out1 edge: (8,2048,2048) = e[row] broadcast.
//
// R6 post-mortem: kernels total ~60us in R4/R5/R6 regardless of structure;
// best fit across R1..R6: edge-write phase ~45us (~3TB/s) fully serialized
// after ~12us MFMA compute. R7: persistent fused kernel, grid=512 (half
// residency), grid-stride over 1024 row-tiles (2 rounds) -> round-1 store
// drain overlaps round-2 compute.

typedef short short8 __attribute__((ext_vector_type(8)));
typedef float floatx4 __attribute__((ext_vector_type(4)));

__device__ __forceinline__ short f2bf(float f) {
    union { float f; unsigned u; } v; v.f = f;
    unsigned r = v.u + 0x7fffu + ((v.u >> 16) & 1u);   // RNE
    return (short)(r >> 16);
}

// d_ws layout (shorts): W1T[256][128] at 0      (w1n^T,  64KB)
//                       W2T[128][256] at 32768  (w2n^T,  64KB)
//                       WET[128][128] at 65536  ((w1e_top+w1e_bot)^T, 32KB)
// Requires ws_size >= 163840 bytes.
__global__ __launch_bounds__(256)
void prep_weights(const float* __restrict__ w1n, const float* __restrict__ w2n,
                  const float* __restrict__ w1e, short* __restrict__ ws)
{
    const int id = blockIdx.x * 256 + threadIdx.x;   // 0..81919
    if (id < 32768) {                                // W1T[n][k] = w1n[k][n]
        const int n = id >> 7, k = id & 127;
        ws[id] = f2bf(w1n[k * 256 + n]);
    } else if (id < 65536) {                         // W2T[n][k] = w2n[k][n]
        const int j = id - 32768;
        const int n = j >> 8, k = j & 255;
        ws[id] = f2bf(w2n[k * 128 + n]);
    } else {                                         // WET[n][k] = sum of halves
        const int j = id - 65536;
        const int n = j >> 7, k = j & 127;
        ws[id] = f2bf(w1e[k * 128 + n] + w1e[(k + 128) * 128 + n]);
    }
}

#define TPB 256
#define ROWS 16
#define NTILES 1024     // 16384 rows / 16
#define GRID 512        // 2 blocks/CU -> 2 grid-stride rounds
#define XS_STRIDE 136   // 128 + 8 pad (bf16)
#define H1_STRIDE 264   // 256 + 8 pad

// MFMA 16x16x32 bf16 lane mapping:
//   A: lane holds A[m = lane&15][k = (lane>>4)*8 + j], j=0..7
//   B: lane holds B[k = (lane>>4)*8 + j][n = lane&15]
//   C/D: reg r holds D[row = (lane>>4)*4 + r][col = lane&15]
__global__ __launch_bounds__(TPB, 2)
void fused_persistent(const float* __restrict__ x,
                      const float* __restrict__ b1n, const float* __restrict__ b2n,
                      const float* __restrict__ b1e,
                      const float* __restrict__ w2e, const float* __restrict__ b2e,
                      const short* __restrict__ wt,
                      float* __restrict__ h_out, float* __restrict__ edge_out)
{
    __shared__ short xs[ROWS * XS_STRIDE];
    __shared__ short h1s[ROWS * H1_STRIDE];
    __shared__ short hbs[ROWS * XS_STRIDE];
    __shared__ float partial[4][ROWS];
    __shared__ float es[ROWS];

    const int t = threadIdx.x;
    const int w = t >> 6;          // wave 0..3
    const int l = t & 63;
    const int l15 = l & 15;
    const int quad = l >> 4;

    const short* __restrict__ W2T = wt + 32768;
    const short* __restrict__ WET = wt + 65536;

    for (int vb = blockIdx.x; vb < NTILES; vb += GRID) {
        const int row0 = vb * ROWS;

        // ---- load 16x128 fp32 tile -> bf16 LDS ----
        // (prev round's pending edge stores drain in background; the barrier
        //  below only waits for store ACK at L2, not HBM drain)
        {
            const float4* __restrict__ x4 = (const float4*)(x + (size_t)row0 * 128);
#pragma unroll
            for (int i = 0; i < 2; ++i) {
                const int fi = t + i * TPB;            // 512 float4 total
                const float4 v = x4[fi];
                const int row = fi >> 5, col = (fi & 31) * 4;
                short4 s;
                s.x = f2bf(v.x); s.y = f2bf(v.y); s.z = f2bf(v.z); s.w = f2bf(v.w);
                *(short4*)&xs[row * XS_STRIDE + col] = s;
            }
        }
        __syncthreads();

        // ---- stage 1: h1 = relu(X @ W1n + b1n)   (16x128)@(128x256) ----
        {
            short8 a1[4];
#pragma unroll
            for (int k = 0; k < 4; ++k)
                a1[k] = *(const short8*)&xs[l15 * XS_STRIDE + k * 32 + quad * 8];

            floatx4 acc1[4];
#pragma unroll
            for (int ci = 0; ci < 4; ++ci) {
                const int ct = 4 * w + ci;
                const float b = b1n[ct * 16 + l15];
                acc1[ci] = (floatx4){b, b, b, b};
#pragma unroll
                for (int k = 0; k < 4; ++k) {
                    const short8 bf = *(const short8*)(wt + (ct * 16 + l15) * 128 + k * 32 + quad * 8);
                    acc1[ci] = __builtin_amdgcn_mfma_f32_16x16x32_bf16(a1[k], bf, acc1[ci], 0, 0, 0);
                }
            }
#pragma unroll
            for (int ci = 0; ci < 4; ++ci) {
                const int ct = 4 * w + ci;
#pragma unroll
                for (int r = 0; r < 4; ++r)
                    h1s[(quad * 4 + r) * H1_STRIDE + ct * 16 + l15] = f2bf(fmaxf(acc1[ci][r], 0.f));
            }
        }
        __syncthreads();

        // ---- stage 2: h = h1 @ W2n + b2n   (16x256)@(256x128) ----
        {
            short8 a2[8];
#pragma unroll
            for (int k = 0; k < 8; ++k)
                a2[k] = *(const short8*)&h1s[l15 * H1_STRIDE + k * 32 + quad * 8];

#pragma unroll
            for (int ci = 0; ci < 2; ++ci) {
                const int ct = 2 * w + ci;
                const float b = b2n[ct * 16 + l15];
                floatx4 acc2 = (floatx4){b, b, b, b};
#pragma unroll
                for (int k = 0; k < 8; ++k) {
                    const short8 bf = *(const short8*)(W2T + (ct * 16 + l15) * 256 + k * 32 + quad * 8);
                    acc2 = __builtin_amdgcn_mfma_f32_16x16x32_bf16(a2[k], bf, acc2, 0, 0, 0);
                }
#pragma unroll
                for (int r = 0; r < 4; ++r) {
                    const int row = quad * 4 + r;
                    const float v = acc2[r];
                    h_out[(size_t)(row0 + row) * 128 + ct * 16 + l15] = v;
                    hbs[row * XS_STRIDE + ct * 16 + l15] = f2bf(v);
                }
            }
        }
        __syncthreads();

        // ---- stage 3+4: t1 = relu(h @ WE + b1e); e = (t1 . w2e + b2e)/2048 ----
        {
            short8 a3[4];
#pragma unroll
            for (int k = 0; k < 4; ++k)
                a3[k] = *(const short8*)&hbs[l15 * XS_STRIDE + k * 32 + quad * 8];

            float p[4] = {0.f, 0.f, 0.f, 0.f};
#pragma unroll
            for (int ci = 0; ci < 2; ++ci) {
                const int ct = 2 * w + ci;
                const float b = b1e[ct * 16 + l15];
                floatx4 acc3 = (floatx4){b, b, b, b};
#pragma unroll
                for (int k = 0; k < 4; ++k) {
                    const short8 bf = *(const short8*)(WET + (ct * 16 + l15) * 128 + k * 32 + quad * 8);
                    acc3 = __builtin_amdgcn_mfma_f32_16x16x32_bf16(a3[k], bf, acc3, 0, 0, 0);
                }
                const float wv = w2e[ct * 16 + l15];
#pragma unroll
                for (int r = 0; r < 4; ++r)
                    p[r] += fmaxf(acc3[r], 0.f) * wv;
            }
#pragma unroll
            for (int off = 8; off >= 1; off >>= 1)
#pragma unroll
                for (int r = 0; r < 4; ++r)
                    p[r] += __shfl_xor(p[r], off, 64);
            if (l15 == 0) {
#pragma unroll
                for (int r = 0; r < 4; ++r)
                    partial[w][quad * 4 + r] = p[r];
            }
        }
        __syncthreads();
        if (t < ROWS) {
            es[t] = (partial[0][t] + partial[1][t] + partial[2][t]
                     + partial[3][t] + b2e[0]) * (1.0f / 2048.0f);
        }
        __syncthreads();

        // ---- stage 5: edge broadcast, 16 rows x 8KB, fire-and-forget ----
        // (no barrier after: stores drain under next round's compute; next
        //  round touches xs/h1s/hbs which are behind >=3 barriers from any
        //  es reader, and es itself is rewritten only after 4 barriers)
        {
            floatx4* __restrict__ e4 = (floatx4*)(edge_out + (size_t)row0 * 2048);
#pragma unroll
            for (int r = 0; r < ROWS; ++r) {
                const float ev = es[r];
                const floatx4 vv = (floatx4){ev, ev, ev, ev};
                e4[r * 512 + t] = vv;
                e4[r * 512 + t + 256] = vv;
            }
        }
    }
}

extern "C" void kernel_launch(void* const* d_in, const int* in_sizes, int n_in,
                              void* d_out, int out_size, void* d_ws, size_t ws_size,
                              hipStream_t stream) {
    const float* x   = (const float*)d_in[0];
    const float* w1n = (const float*)d_in[1];
    const float* b1n = (const float*)d_in[2];
    const float* w2n = (const float*)d_in[3];
    const float* b2n = (const float*)d_in[4];
    const float* w1e = (const float*)d_in[5];
    const float* b1e = (const float*)d_in[6];
    const float* w2e = (const float*)d_in[7];
    const float* b2e = (const float*)d_in[8];

    float* h_out    = (float*)d_out;                              // (8,2048,128)
    float* edge_out = (float*)d_out + (size_t)8 * 2048 * 128;     // (8,2048,2048)
    short* wt       = (short*)d_ws;                               // 160 KB bf16 weights

    prep_weights<<<dim3(320), dim3(256), 0, stream>>>(w1n, w2n, w1e, wt);
    fused_persistent<<<dim3(GRID), dim3(TPB), 0, stream>>>(
        x, b1n, b2n, b1e, w2e, b2e, wt, h_out, edge_out);
}

// Round 8
// 164.561 us; speedup vs baseline: 1.1181x; 1.0563x over previous
//
#include <hip/hip_runtime.h>

// Shapes: N=8, M=2048 -> 16384 rows; D=128, L=128.
// out0 h: (16384,128) fp32; out1 edge: (8,2048,2048) = e[row] broadcast.
//
// R7 post-mortem: overlap win confirmed; best-fit model says compute phase
// ~18.5us/round dominated by MFMA B-fragment GATHERS (64 lanes x 16B at
// stride 256B = >=16 transactions/load). R8: pre-swizzle weights in d_ws
// into fragment order so every weight load is one coalesced 1-KB
// global_load_dwordx4. Structure otherwise identical to R7.

typedef short short8 __attribute__((ext_vector_type(8)));
typedef float floatx4 __attribute__((ext_vector_type(4)));

__device__ __forceinline__ short f2bf(float f) {
    union { float f; unsigned u; } v; v.f = f;
    unsigned r = v.u + 0x7fffu + ((v.u >> 16) & 1u);   // RNE
    return (short)(r >> 16);
}

// d_ws (shorts), all in MFMA-fragment order:
//   W1S at 0      (64KB): idx = ((ct*4+k)*64 + l)*8 + j, ct 0..15, k 0..3
//       value = bf16(w1n[(k*32 + (l>>4)*8 + j)*256 + ct*16 + (l&15)])
//   W2S at 32768  (64KB): idx = ((ct*8+k)*64 + l)*8 + j, ct 0..7, k 0..7
//       value = bf16(w2n[(k*32 + (l>>4)*8 + j)*128 + ct*16 + (l&15)])
//   WES at 65536  (32KB): idx = ((ct*4+k)*64 + l)*8 + j, ct 0..7, k 0..3
//       value = bf16(sum of w1e halves, same indexing as W2S cols)
// Requires ws_size >= 163840 bytes.
__global__ __launch_bounds__(256)
void prep_weights(const float* __restrict__ w1n, const float* __restrict__ w2n,
                  const float* __restrict__ w1e, short* __restrict__ ws)
{
    const int id = blockIdx.x * 256 + threadIdx.x;   // 0..81919
    const int j = id & 7;
    if (id < 32768) {
        const int g = id >> 3, l = g & 63, ctk = g >> 6;
        const int ct = ctk >> 2, k = ctk & 3;
        const int kg = k * 32 + (l >> 4) * 8 + j;
        ws[id] = f2bf(w1n[kg * 256 + ct * 16 + (l & 15)]);
    } else if (id < 65536) {
        const int g = (id - 32768) >> 3, l = g & 63, ctk = g >> 6;
        const int ct = ctk >> 3, k = ctk & 7;
        const int kg = k * 32 + (l >> 4) * 8 + j;
        ws[id] = f2bf(w2n[kg * 128 + ct * 16 + (l & 15)]);
    } else {
        const int g = (id - 65536) >> 3, l = g & 63, ctk = g >> 6;
        const int ct = ctk >> 2, k = ctk & 3;
        const int kg = k * 32 + (l >> 4) * 8 + j;
        ws[id] = f2bf(w1e[kg * 128 + ct * 16 + (l & 15)]
                      + w1e[(kg + 128) * 128 + ct * 16 + (l & 15)]);
    }
}

#define TPB 256
#define ROWS 16
#define NTILES 1024     // 16384 rows / 16
#define GRID 512        // 2 blocks/CU -> 2 grid-stride rounds
#define XS_STRIDE 136   // 128 + 8 pad (bf16)
#define H1_STRIDE 264   // 256 + 8 pad

// MFMA 16x16x32 bf16 lane mapping:
//   A: lane holds A[m = lane&15][k = (lane>>4)*8 + j], j=0..7
//   B: lane holds B[k = (lane>>4)*8 + j][n = lane&15]
//   C/D: reg r holds D[row = (lane>>4)*4 + r][col = lane&15]
__global__ __launch_bounds__(TPB, 2)
void fused_persistent(const float* __restrict__ x,
                      const float* __restrict__ b1n, const float* __restrict__ b2n,
                      const float* __restrict__ b1e,
                      const float* __restrict__ w2e, const float* __restrict__ b2e,
                      const short* __restrict__ wt,
                      float* __restrict__ h_out, float* __restrict__ edge_out)
{
    __shared__ short xs[ROWS * XS_STRIDE];
    __shared__ short h1s[ROWS * H1_STRIDE];
    __shared__ short hbs[ROWS * XS_STRIDE];
    __shared__ float partial[4][ROWS];
    __shared__ float es[ROWS];

    const int t = threadIdx.x;
    const int w = t >> 6;          // wave 0..3
    const int l = t & 63;
    const int l15 = l & 15;
    const int quad = l >> 4;

    const short* __restrict__ W2S = wt + 32768;
    const short* __restrict__ WES = wt + 65536;

    for (int vb = blockIdx.x; vb < NTILES; vb += GRID) {
        const int row0 = vb * ROWS;

        // ---- load 16x128 fp32 tile -> bf16 LDS ----
        {
            const float4* __restrict__ x4 = (const float4*)(x + (size_t)row0 * 128);
#pragma unroll
            for (int i = 0; i < 2; ++i) {
                const int fi = t + i * TPB;            // 512 float4 total
                const float4 v = x4[fi];
                const int row = fi >> 5, col = (fi & 31) * 4;
                short4 s;
                s.x = f2bf(v.x); s.y = f2bf(v.y); s.z = f2bf(v.z); s.w = f2bf(v.w);
                *(short4*)&xs[row * XS_STRIDE + col] = s;
            }
        }
        __syncthreads();

        // ---- stage 1: h1 = relu(X @ W1n + b1n)   (16x128)@(128x256) ----
        {
            short8 a1[4];
#pragma unroll
            for (int k = 0; k < 4; ++k)
                a1[k] = *(const short8*)&xs[l15 * XS_STRIDE + k * 32 + quad * 8];

            floatx4 acc1[4];
#pragma unroll
            for (int ci = 0; ci < 4; ++ci) {
                const int ct = 4 * w + ci;
                const float b = b1n[ct * 16 + l15];
                acc1[ci] = (floatx4){b, b, b, b};
#pragma unroll
                for (int k = 0; k < 4; ++k) {
                    const short8 bf = *(const short8*)(wt + ((ct * 4 + k) * 64 + l) * 8);
                    acc1[ci] = __builtin_amdgcn_mfma_f32_16x16x32_bf16(a1[k], bf, acc1[ci], 0, 0, 0);
                }
            }
#pragma unroll
            for (int ci = 0; ci < 4; ++ci) {
                const int ct = 4 * w + ci;
#pragma unroll
                for (int r = 0; r < 4; ++r)
                    h1s[(quad * 4 + r) * H1_STRIDE + ct * 16 + l15] = f2bf(fmaxf(acc1[ci][r], 0.f));
            }
        }
        __syncthreads();

        // ---- stage 2: h = h1 @ W2n + b2n   (16x256)@(256x128) ----
        {
            short8 a2[8];
#pragma unroll
            for (int k = 0; k < 8; ++k)
                a2[k] = *(const short8*)&h1s[l15 * H1_STRIDE + k * 32 + quad * 8];

#pragma unroll
            for (int ci = 0; ci < 2; ++ci) {
                const int ct = 2 * w + ci;
                const float b = b2n[ct * 16 + l15];
                floatx4 acc2 = (floatx4){b, b, b, b};
#pragma unroll
                for (int k = 0; k < 8; ++k) {
                    const short8 bf = *(const short8*)(W2S + ((ct * 8 + k) * 64 + l) * 8);
                    acc2 = __builtin_amdgcn_mfma_f32_16x16x32_bf16(a2[k], bf, acc2, 0, 0, 0);
                }
#pragma unroll
                for (int r = 0; r < 4; ++r) {
                    const int row = quad * 4 + r;
                    const float v = acc2[r];
                    h_out[(size_t)(row0 + row) * 128 + ct * 16 + l15] = v;
                    hbs[row * XS_STRIDE + ct * 16 + l15] = f2bf(v);
                }
            }
        }
        __syncthreads();

        // ---- stage 3+4: t1 = relu(h @ WE + b1e); e = (t1 . w2e + b2e)/2048 ----
        {
            short8 a3[4];
#pragma unroll
            for (int k = 0; k < 4; ++k)
                a3[k] = *(const short8*)&hbs[l15 * XS_STRIDE + k * 32 + quad * 8];

            float p[4] = {0.f, 0.f, 0.f, 0.f};
#pragma unroll
            for (int ci = 0; ci < 2; ++ci) {
                const int ct = 2 * w + ci;
                const float b = b1e[ct * 16 + l15];
                floatx4 acc3 = (floatx4){b, b, b, b};
#pragma unroll
                for (int k = 0; k < 4; ++k) {
                    const short8 bf = *(const short8*)(WES + ((ct * 4 + k) * 64 + l) * 8);
                    acc3 = __builtin_amdgcn_mfma_f32_16x16x32_bf16(a3[k], bf, acc3, 0, 0, 0);
                }
                const float wv = w2e[ct * 16 + l15];
#pragma unroll
                for (int r = 0; r < 4; ++r)
                    p[r] += fmaxf(acc3[r], 0.f) * wv;
            }
#pragma unroll
            for (int off = 8; off >= 1; off >>= 1)
#pragma unroll
                for (int r = 0; r < 4; ++r)
                    p[r] += __shfl_xor(p[r], off, 64);
            if (l15 == 0) {
#pragma unroll
                for (int r = 0; r < 4; ++r)
                    partial[w][quad * 4 + r] = p[r];
            }
        }
        __syncthreads();
        if (t < ROWS) {
            es[t] = (partial[0][t] + partial[1][t] + partial[2][t]
                     + partial[3][t] + b2e[0]) * (1.0f / 2048.0f);
        }
        __syncthreads();

        // ---- stage 5: edge broadcast, 16 rows x 8KB, fire-and-forget ----
        {
            floatx4* __restrict__ e4 = (floatx4*)(edge_out + (size_t)row0 * 2048);
#pragma unroll
            for (int r = 0; r < ROWS; ++r) {
                const float ev = es[r];
                const floatx4 vv = (floatx4){ev, ev, ev, ev};
                e4[r * 512 + t] = vv;
                e4[r * 512 + t + 256] = vv;
            }
        }
    }
}

extern "C" void kernel_launch(void* const* d_in, const int* in_sizes, int n_in,
                              void* d_out, int out_size, void* d_ws, size_t ws_size,
                              hipStream_t stream) {
    const float* x   = (const float*)d_in[0];
    const float* w1n = (const float*)d_in[1];
    const float* b1n = (const float*)d_in[2];
    const float* w2n = (const float*)d_in[3];
    const float* b2n = (const float*)d_in[4];
    const float* w1e = (const float*)d_in[5];
    const float* b1e = (const float*)d_in[6];
    const float* w2e = (const float*)d_in[7];
    const float* b2e = (const float*)d_in[8];

    float* h_out    = (float*)d_out;                              // (8,2048,128)
    float* edge_out = (float*)d_out + (size_t)8 * 2048 * 128;     // (8,2048,2048)
    short* wt       = (short*)d_ws;                               // 160 KB swizzled bf16 weights

    prep_weights<<<dim3(320), dim3(256), 0, stream>>>(w1n, w2n, w1e, wt);
    fused_persistent<<<dim3(GRID), dim3(TPB), 0, stream>>>(
        x, b1n, b2n, b1e, w2e, b2e, wt, h_out, edge_out);
}